// Round 1
// baseline (283.039 us; speedup 1.0000x reference)
//
#include <hip/hip_runtime.h>
#include <math.h>

#define EPS 1e-8f

__device__ __forceinline__ float softplus_f(float x) {
    return (x > 20.0f) ? x : log1pf(expf(x));
}
__device__ __forceinline__ float sigmoid_f(float x) {
    return 1.0f / (1.0f + expf(-x));
}

// -------------------------------------------------------------------------
// Kernel 0: preprocess controls.
// grid = B blocks, 256 threads (wave h handles head h, lane = w).
// controls layout per b (792 floats): keys[4][64] | erase[4][64] | write[4][64]
//   | betas[4] | gates[4] | shifts[4][3] | gammas[4]
// params[bh*8]: {beta, gate, s0, s1, s2, gamma, keynorm, pad}
// -------------------------------------------------------------------------
__global__ void prep_kernel(const float* __restrict__ controls,
                            float* __restrict__ keys,
                            float* __restrict__ params,
                            float* __restrict__ erase,
                            float* __restrict__ writev)
{
    int b = blockIdx.x;
    int t = threadIdx.x;
    int h = t >> 6;     // 0..3 (wave id)
    int w = t & 63;
    const float* c = controls + (size_t)b * 792;

    float kt = tanhf(c[h * 64 + w]);
    int bh = b * 4 + h;
    keys[bh * 64 + w]   = kt;
    erase[bh * 64 + w]  = sigmoid_f(c[256 + h * 64 + w]);
    writev[bh * 64 + w] = tanhf(c[512 + h * 64 + w]);

    // wave-reduce ||tanh(key)||^2 over 64 lanes
    float nsq = kt * kt;
    #pragma unroll
    for (int m = 1; m < 64; m <<= 1) nsq += __shfl_xor(nsq, m, 64);

    if (w == 0) {
        float beta  = softplus_f(c[768 + h]);
        float gate  = sigmoid_f(c[772 + h]);
        float r0 = c[776 + h * 3 + 0];
        float r1 = c[776 + h * 3 + 1];
        float r2 = c[776 + h * 3 + 2];
        float mx = fmaxf(r0, fmaxf(r1, r2));
        float e0 = expf(r0 - mx), e1 = expf(r1 - mx), e2 = expf(r2 - mx);
        float inv = 1.0f / (e0 + e1 + e2);
        float gamma = 1.0f + softplus_f(c[788 + h]);
        float* p = params + bh * 8;
        p[0] = beta; p[1] = gate;
        p[2] = e0 * inv; p[3] = e1 * inv; p[4] = e2 * inv;
        p[5] = gamma; p[6] = sqrtf(nsq); p[7] = 0.0f;
    }
}

// -------------------------------------------------------------------------
// Kernel A: scores[b,h,n] = beta[h] * dot(keys[h], mem[b,n]) /
//                           (|mem[b,n]| * |keys[h]| + EPS)
// block = 256 threads = 16 rows x 16 lanes (float4 per lane).
// grid = (N/16, B)
// -------------------------------------------------------------------------
__global__ void score_kernel(const float* __restrict__ memory,
                             const float* __restrict__ keys,
                             const float* __restrict__ params,
                             float* __restrict__ scores, int N)
{
    int b = blockIdx.y;
    int nbase = blockIdx.x * 16;
    int t = threadIdx.x;
    int row = t >> 4;     // 0..15
    int lane = t & 15;    // 0..15
    int n = nbase + row;

    __shared__ float kk[4 * 64];
    __shared__ float betas[4], knorm[4];
    __shared__ float sc[4][16];

    kk[t] = keys[(size_t)b * 256 + t];
    if (t < 4) {
        betas[t] = params[((size_t)b * 4 + t) * 8 + 0];
        knorm[t] = params[((size_t)b * 4 + t) * 8 + 6];
    }
    __syncthreads();

    const float4 m4 = ((const float4*)(memory + ((size_t)b * N + n) * 64))[lane];
    float nsq = m4.x * m4.x + m4.y * m4.y + m4.z * m4.z + m4.w * m4.w;
    float d[4];
    #pragma unroll
    for (int h = 0; h < 4; h++) {
        float4 k4 = ((const float4*)(kk + h * 64))[lane];
        d[h] = m4.x * k4.x + m4.y * k4.y + m4.z * k4.z + m4.w * k4.w;
    }
    // reduce over 16 lanes of the row
    #pragma unroll
    for (int m = 1; m < 16; m <<= 1) {
        nsq += __shfl_xor(nsq, m, 64);
        #pragma unroll
        for (int h = 0; h < 4; h++) d[h] += __shfl_xor(d[h], m, 64);
    }
    if (lane == 0) {
        float mn = sqrtf(nsq);
        #pragma unroll
        for (int h = 0; h < 4; h++)
            sc[h][row] = betas[h] * d[h] / (mn * knorm[h] + EPS);
    }
    __syncthreads();
    if (t < 64) {
        int h = t >> 4, i = t & 15;
        scores[((size_t)b * 4 + h) * N + nbase + i] = sc[h][i];
    }
}

// -------------------------------------------------------------------------
// Kernel B: the softmax -> interp -> shift -> sharpen -> normalize chain.
// One 1024-thread block per (b,h). In-place: scores row -> w_dist row.
// -------------------------------------------------------------------------
__device__ __forceinline__ float block_reduce_sum(float v, float* red) {
    #pragma unroll
    for (int m = 1; m < 64; m <<= 1) v += __shfl_xor(v, m, 64);
    int wid = threadIdx.x >> 6;
    __syncthreads();
    if ((threadIdx.x & 63) == 0) red[wid] = v;
    __syncthreads();
    float r = red[0];
    #pragma unroll
    for (int i = 1; i < 16; i++) r += red[i];
    return r;
}
__device__ __forceinline__ float block_reduce_max(float v, float* red) {
    #pragma unroll
    for (int m = 1; m < 64; m <<= 1) v = fmaxf(v, __shfl_xor(v, m, 64));
    int wid = threadIdx.x >> 6;
    __syncthreads();
    if ((threadIdx.x & 63) == 0) red[wid] = v;
    __syncthreads();
    float r = red[0];
    #pragma unroll
    for (int i = 1; i < 16; i++) r = fmaxf(r, red[i]);
    return r;
}

__global__ __launch_bounds__(1024)
void weights_kernel(float* __restrict__ scores,
                    const float* __restrict__ prev,
                    const float* __restrict__ params, int N)
{
    int bh = blockIdx.x;
    int t = threadIdx.x;
    const float* p = params + (size_t)bh * 8;
    float gate = p[1], s0 = p[2], s1 = p[3], s2 = p[4], gamma = p[5];

    __shared__ float wi_s[8192];
    __shared__ float red[16];

    float* srow = scores + (size_t)bh * N;
    const float* prow = prev + (size_t)bh * N;

    const int K = N / 1024;   // 8
    float sv[8];
    #pragma unroll
    for (int k = 0; k < 8; k++) sv[k] = srow[t + k * 1024];

    float mx = sv[0];
    #pragma unroll
    for (int k = 1; k < 8; k++) mx = fmaxf(mx, sv[k]);
    mx = block_reduce_max(mx, red);

    float e[8]; float lsum = 0.0f;
    #pragma unroll
    for (int k = 0; k < 8; k++) { e[k] = expf(sv[k] - mx); lsum += e[k]; }
    float S = block_reduce_sum(lsum, red);
    float invS = 1.0f / S;

    float om_gate = 1.0f - gate;
    #pragma unroll
    for (int k = 0; k < 8; k++) {
        int i = t + k * 1024;
        float wc = e[k] * invS;
        wi_s[i] = gate * wc + om_gate * prow[i];
    }
    __syncthreads();

    float wsv[8]; float lsum2 = 0.0f;
    #pragma unroll
    for (int k = 0; k < 8; k++) {
        int i = t + k * 1024;
        int im1 = (i == 0) ? (N - 1) : (i - 1);
        int ip1 = (i == N - 1) ? 0 : (i + 1);
        float wshift = s0 * wi_s[im1] + s1 * wi_s[i] + s2 * wi_s[ip1];
        float wp = powf(wshift, gamma);
        wsv[k] = wp; lsum2 += wp;
    }
    float T = block_reduce_sum(lsum2, red);
    float invT = 1.0f / (T + EPS);
    #pragma unroll
    for (int k = 0; k < 8; k++) srow[t + k * 1024] = wsv[k] * invT;
    (void)K;
}

// -------------------------------------------------------------------------
// Kernel C: out[b,n,w] = mem[b,n,w] * prod_h(1 - wd[b,h,n]*erase[h,w])
//                        + sum_h wd[b,h,n]*write[h,w]
// block = 256 threads = 16 rows x 16 lanes (float4). grid = B*N/16.
// -------------------------------------------------------------------------
__global__ void output_kernel(const float* __restrict__ memory,
                              const float* __restrict__ wdist,
                              const float* __restrict__ erase,
                              const float* __restrict__ writev,
                              float* __restrict__ out, int N)
{
    int t = threadIdx.x;
    int rowsPerB = N / 16;
    int b = blockIdx.x / rowsPerB;
    int nbase = (blockIdx.x % rowsPerB) * 16;

    __shared__ float es[256], wv[256];
    __shared__ float wd_s[4][16];
    es[t] = erase[(size_t)b * 256 + t];
    wv[t] = writev[(size_t)b * 256 + t];
    if (t < 64) {
        int h = t >> 4, i = t & 15;
        wd_s[h][i] = wdist[((size_t)b * 4 + h) * N + nbase + i];
    }
    __syncthreads();

    int row = t >> 4, lane = t & 15;
    int n = nbase + row;
    const float4 m4 = ((const float4*)(memory + ((size_t)b * N + n) * 64))[lane];

    float4 pe = make_float4(1.f, 1.f, 1.f, 1.f);
    float4 up = make_float4(0.f, 0.f, 0.f, 0.f);
    #pragma unroll
    for (int h = 0; h < 4; h++) {
        float f = wd_s[h][row];
        float4 e4 = ((const float4*)(es + h * 64))[lane];
        float4 w4 = ((const float4*)(wv + h * 64))[lane];
        pe.x *= 1.0f - f * e4.x;  pe.y *= 1.0f - f * e4.y;
        pe.z *= 1.0f - f * e4.z;  pe.w *= 1.0f - f * e4.w;
        up.x += f * w4.x;  up.y += f * w4.y;
        up.z += f * w4.z;  up.w += f * w4.w;
    }
    float4 o;
    o.x = m4.x * pe.x + up.x;
    o.y = m4.y * pe.y + up.y;
    o.z = m4.z * pe.z + up.z;
    o.w = m4.w * pe.w + up.w;
    ((float4*)(out + ((size_t)b * N + n) * 64))[lane] = o;
}

// -------------------------------------------------------------------------
extern "C" void kernel_launch(void* const* d_in, const int* in_sizes, int n_in,
                              void* d_out, int out_size, void* d_ws, size_t ws_size,
                              hipStream_t stream) {
    const float* memory   = (const float*)d_in[0];
    const float* controls = (const float*)d_in[1];
    const float* prev     = (const float*)d_in[2];
    float* out = (float*)d_out;

    int B = in_sizes[1] / 792;            // H*(3W+6) = 792
    int N = in_sizes[0] / (B * 64);       // W = 64

    float* wsf    = (float*)d_ws;
    float* keys   = wsf;                          // B*4*64
    float* params = keys   + (size_t)B * 256;     // B*4*8
    float* erase  = params + (size_t)B * 32;      // B*4*64
    float* writev = erase  + (size_t)B * 256;     // B*4*64
    float* scores = writev + (size_t)B * 256;     // B*4*N (becomes w_dist in-place)

    prep_kernel<<<B, 256, 0, stream>>>(controls, keys, params, erase, writev);
    score_kernel<<<dim3(N / 16, B), 256, 0, stream>>>(memory, keys, params, scores, N);
    weights_kernel<<<B * 4, 1024, 0, stream>>>(scores, prev, params, N);
    output_kernel<<<B * (N / 16), 256, 0, stream>>>(memory, scores, erase, writev, out, N);
}

// Round 2
// 271.673 us; speedup vs baseline: 1.0418x; 1.0418x over previous
//
#include <hip/hip_runtime.h>
#include <math.h>

#define EPS 1e-8f

__device__ __forceinline__ float softplus_f(float x) {
    return (x > 20.0f) ? x : log1pf(expf(x));
}
__device__ __forceinline__ float sigmoid_f(float x) {
    return 1.0f / (1.0f + expf(-x));
}

// -------------------------------------------------------------------------
// Kernel 0: preprocess controls.
// grid = B blocks, 256 threads (wave h handles head h, lane = w).
// controls per b (792 f): keys[4][64] | erase[4][64] | write[4][64]
//   | betas[4] | gates[4] | shifts[4][3] | gammas[4]
// params[bh*8]: {beta, gate, s0, s1, s2, gamma, keynorm, pad}
// -------------------------------------------------------------------------
__global__ void prep_kernel(const float* __restrict__ controls,
                            float* __restrict__ keys,
                            float* __restrict__ params,
                            float* __restrict__ erase,
                            float* __restrict__ writev)
{
    int b = blockIdx.x;
    int t = threadIdx.x;
    int h = t >> 6;
    int w = t & 63;
    const float* c = controls + (size_t)b * 792;

    float kt = tanhf(c[h * 64 + w]);
    int bh = b * 4 + h;
    keys[bh * 64 + w]   = kt;
    erase[bh * 64 + w]  = sigmoid_f(c[256 + h * 64 + w]);
    writev[bh * 64 + w] = tanhf(c[512 + h * 64 + w]);

    float nsq = kt * kt;
    #pragma unroll
    for (int m = 1; m < 64; m <<= 1) nsq += __shfl_xor(nsq, m, 64);

    if (w == 0) {
        float beta  = softplus_f(c[768 + h]);
        float gate  = sigmoid_f(c[772 + h]);
        float r0 = c[776 + h * 3 + 0];
        float r1 = c[776 + h * 3 + 1];
        float r2 = c[776 + h * 3 + 2];
        float mx = fmaxf(r0, fmaxf(r1, r2));
        float e0 = expf(r0 - mx), e1 = expf(r1 - mx), e2 = expf(r2 - mx);
        float inv = 1.0f / (e0 + e1 + e2);
        float gamma = 1.0f + softplus_f(c[788 + h]);
        float* p = params + bh * 8;
        p[0] = beta; p[1] = gate;
        p[2] = e0 * inv; p[3] = e1 * inv; p[4] = e2 * inv;
        p[5] = gamma; p[6] = sqrtf(nsq); p[7] = 0.0f;
    }
}

// -------------------------------------------------------------------------
// Kernel A: scores[b,h,n] = beta*dot(keys,mem)/(|mem|*|keys|+EPS)
// block = 256 threads; 64 rows per block; thread = (rq = t>>4, lane = t&15),
// handles rows rq+16j, j=0..3. 4 independent float4 loads per thread for ILP.
// grid = (N/64, B)
// -------------------------------------------------------------------------
__global__ __launch_bounds__(256)
void score_kernel(const float* __restrict__ memory,
                  const float* __restrict__ keys,
                  const float* __restrict__ params,
                  float* __restrict__ scores, int N)
{
    int b = blockIdx.y;
    int nbase = blockIdx.x * 64;
    int t = threadIdx.x;
    int rq = t >> 4;      // 0..15
    int lane = t & 15;    // 0..15

    __shared__ float kk[256];
    __shared__ float betas[4], knorm[4];
    __shared__ float sc[4][64];

    kk[t] = keys[(size_t)b * 256 + t];
    if (t < 4) {
        betas[t] = params[((size_t)b * 4 + t) * 8 + 0];
        knorm[t] = params[((size_t)b * 4 + t) * 8 + 6];
    }
    __syncthreads();

    float4 k4[4];
    #pragma unroll
    for (int h = 0; h < 4; h++) k4[h] = ((const float4*)(kk + h * 64))[lane];

    // prefetch 4 rows (independent loads in flight)
    float4 m4[4];
    #pragma unroll
    for (int j = 0; j < 4; j++) {
        int n = nbase + rq + 16 * j;
        m4[j] = ((const float4*)(memory + ((size_t)b * N + n) * 64))[lane];
    }

    #pragma unroll
    for (int j = 0; j < 4; j++) {
        float nsq = m4[j].x * m4[j].x + m4[j].y * m4[j].y
                  + m4[j].z * m4[j].z + m4[j].w * m4[j].w;
        float d[4];
        #pragma unroll
        for (int h = 0; h < 4; h++) {
            d[h] = m4[j].x * k4[h].x + m4[j].y * k4[h].y
                 + m4[j].z * k4[h].z + m4[j].w * k4[h].w;
        }
        #pragma unroll
        for (int m = 1; m < 16; m <<= 1) {
            nsq += __shfl_xor(nsq, m, 64);
            #pragma unroll
            for (int h = 0; h < 4; h++) d[h] += __shfl_xor(d[h], m, 64);
        }
        if (lane == 0) {
            float mn = sqrtf(nsq);
            int row = rq + 16 * j;
            #pragma unroll
            for (int h = 0; h < 4; h++)
                sc[h][row] = betas[h] * d[h] / (mn * knorm[h] + EPS);
        }
    }
    __syncthreads();
    // 256 threads write 256 values: wave h writes 64 consecutive floats
    scores[((size_t)b * 4 + (t >> 6)) * N + nbase + (t & 63)] = sc[t >> 6][t & 63];
}

// -------------------------------------------------------------------------
// Kernel B: softmax -> interp -> shift -> sharpen -> normalize, one
// 1024-thread block per (b,h); float4 I/O; in-place scores -> w_dist.
// -------------------------------------------------------------------------
__device__ __forceinline__ float block_reduce_sum(float v, float* red) {
    #pragma unroll
    for (int m = 1; m < 64; m <<= 1) v += __shfl_xor(v, m, 64);
    int wid = threadIdx.x >> 6;
    __syncthreads();
    if ((threadIdx.x & 63) == 0) red[wid] = v;
    __syncthreads();
    float r = red[0];
    #pragma unroll
    for (int i = 1; i < 16; i++) r += red[i];
    return r;
}
__device__ __forceinline__ float block_reduce_max(float v, float* red) {
    #pragma unroll
    for (int m = 1; m < 64; m <<= 1) v = fmaxf(v, __shfl_xor(v, m, 64));
    int wid = threadIdx.x >> 6;
    __syncthreads();
    if ((threadIdx.x & 63) == 0) red[wid] = v;
    __syncthreads();
    float r = red[0];
    #pragma unroll
    for (int i = 1; i < 16; i++) r = fmaxf(r, red[i]);
    return r;
}

__global__ __launch_bounds__(1024)
void weights_kernel(float* __restrict__ scores,
                    const float* __restrict__ prev,
                    const float* __restrict__ params, int N)
{
    int bh = blockIdx.x;
    int t = threadIdx.x;
    const float* p = params + (size_t)bh * 8;
    float gate = p[1], s0 = p[2], s1 = p[3], s2 = p[4], gamma = p[5];

    __shared__ float wi_s[8192];
    __shared__ float red[16];

    float* srow = scores + (size_t)bh * N;
    const float* prow = prev + (size_t)bh * N;
    int half = N >> 1;                    // 4096
    int i0 = 4 * t, i1 = half + 4 * t;    // two float4 chunks per thread

    float4 sa = ((const float4*)srow)[t];
    float4 sb = ((const float4*)srow)[half / 4 + t];
    float4 pa = ((const float4*)prow)[t];
    float4 pb = ((const float4*)prow)[half / 4 + t];

    float mx = fmaxf(fmaxf(fmaxf(sa.x, sa.y), fmaxf(sa.z, sa.w)),
                     fmaxf(fmaxf(sb.x, sb.y), fmaxf(sb.z, sb.w)));
    mx = block_reduce_max(mx, red);

    float ea[4] = { __expf(sa.x - mx), __expf(sa.y - mx), __expf(sa.z - mx), __expf(sa.w - mx) };
    float eb[4] = { __expf(sb.x - mx), __expf(sb.y - mx), __expf(sb.z - mx), __expf(sb.w - mx) };
    float lsum = ea[0] + ea[1] + ea[2] + ea[3] + eb[0] + eb[1] + eb[2] + eb[3];
    float S = block_reduce_sum(lsum, red);
    float invS = 1.0f / S;

    float og = 1.0f - gate;
    float pv_a[4] = { pa.x, pa.y, pa.z, pa.w };
    float pv_b[4] = { pb.x, pb.y, pb.z, pb.w };
    #pragma unroll
    for (int k = 0; k < 4; k++) {
        wi_s[i0 + k] = gate * (ea[k] * invS) + og * pv_a[k];
        wi_s[i1 + k] = gate * (eb[k] * invS) + og * pv_b[k];
    }
    __syncthreads();

    float wsv[8]; float lsum2 = 0.0f;
    #pragma unroll
    for (int c = 0; c < 2; c++) {
        int base = (c == 0) ? i0 : i1;
        #pragma unroll
        for (int k = 0; k < 4; k++) {
            int i = base + k;
            int im1 = (i == 0) ? (N - 1) : (i - 1);
            int ip1 = (i == N - 1) ? 0 : (i + 1);
            float ws = s0 * wi_s[im1] + s1 * wi_s[i] + s2 * wi_s[ip1];
            // ws > 0 strictly (softmax>0, prev>=0, gate in (0,1)) -> fast pow
            float wp = __expf(gamma * __logf(ws));
            wsv[c * 4 + k] = wp; lsum2 += wp;
        }
    }
    float T = block_reduce_sum(lsum2, red);
    float invT = 1.0f / (T + EPS);

    float4 oa = make_float4(wsv[0] * invT, wsv[1] * invT, wsv[2] * invT, wsv[3] * invT);
    float4 ob = make_float4(wsv[4] * invT, wsv[5] * invT, wsv[6] * invT, wsv[7] * invT);
    ((float4*)srow)[t] = oa;
    ((float4*)srow)[half / 4 + t] = ob;
}

// -------------------------------------------------------------------------
// Kernel C: out[b,n,w] = mem * prod_h(1 - wd[h,n]*erase[h,w]) + sum_h wd*write
// block = 256 threads; 64 rows/block; 4 rows per thread (4 float4 in flight).
// grid = B * N/64.
// -------------------------------------------------------------------------
__global__ __launch_bounds__(256)
void output_kernel(const float* __restrict__ memory,
                   const float* __restrict__ wdist,
                   const float* __restrict__ erase,
                   const float* __restrict__ writev,
                   float* __restrict__ out, int N)
{
    int t = threadIdx.x;
    int blocksPerB = N >> 6;
    int b = blockIdx.x / blocksPerB;
    int nbase = (blockIdx.x % blocksPerB) << 6;

    __shared__ float es[256], wv[256], wd_s[256];
    es[t] = erase[(size_t)b * 256 + t];
    wv[t] = writev[(size_t)b * 256 + t];
    wd_s[t] = wdist[((size_t)b * 4 + (t >> 6)) * N + nbase + (t & 63)];
    __syncthreads();

    int rq = t >> 4, lane = t & 15;

    float4 e4[4], w4[4];
    #pragma unroll
    for (int h = 0; h < 4; h++) {
        e4[h] = ((const float4*)(es + h * 64))[lane];
        w4[h] = ((const float4*)(wv + h * 64))[lane];
    }

    float4 m4[4];
    #pragma unroll
    for (int j = 0; j < 4; j++) {
        int n = nbase + rq + 16 * j;
        m4[j] = ((const float4*)(memory + ((size_t)b * N + n) * 64))[lane];
    }

    #pragma unroll
    for (int j = 0; j < 4; j++) {
        int row = rq + 16 * j;
        int n = nbase + row;
        float4 pe = make_float4(1.f, 1.f, 1.f, 1.f);
        float4 up = make_float4(0.f, 0.f, 0.f, 0.f);
        #pragma unroll
        for (int h = 0; h < 4; h++) {
            float f = wd_s[h * 64 + row];
            pe.x *= 1.0f - f * e4[h].x;  pe.y *= 1.0f - f * e4[h].y;
            pe.z *= 1.0f - f * e4[h].z;  pe.w *= 1.0f - f * e4[h].w;
            up.x += f * w4[h].x;  up.y += f * w4[h].y;
            up.z += f * w4[h].z;  up.w += f * w4[h].w;
        }
        float4 o;
        o.x = m4[j].x * pe.x + up.x;
        o.y = m4[j].y * pe.y + up.y;
        o.z = m4[j].z * pe.z + up.z;
        o.w = m4[j].w * pe.w + up.w;
        ((float4*)(out + ((size_t)b * N + n) * 64))[lane] = o;
    }
}

// -------------------------------------------------------------------------
extern "C" void kernel_launch(void* const* d_in, const int* in_sizes, int n_in,
                              void* d_out, int out_size, void* d_ws, size_t ws_size,
                              hipStream_t stream) {
    const float* memory   = (const float*)d_in[0];
    const float* controls = (const float*)d_in[1];
    const float* prev     = (const float*)d_in[2];
    float* out = (float*)d_out;

    int B = in_sizes[1] / 792;            // H*(3W+6) = 792
    int N = in_sizes[0] / (B * 64);       // W = 64

    float* wsf    = (float*)d_ws;
    float* keys   = wsf;                          // B*4*64
    float* params = keys   + (size_t)B * 256;     // B*4*8
    float* erase  = params + (size_t)B * 32;      // B*4*64
    float* writev = erase  + (size_t)B * 256;     // B*4*64
    float* scores = writev + (size_t)B * 256;     // B*4*N (in-place -> w_dist)

    prep_kernel<<<B, 256, 0, stream>>>(controls, keys, params, erase, writev);
    score_kernel<<<dim3(N / 64, B), 256, 0, stream>>>(memory, keys, params, scores, N);
    weights_kernel<<<B * 4, 1024, 0, stream>>>(scores, prev, params, N);
    output_kernel<<<B * (N / 64), 256, 0, stream>>>(memory, scores, erase, writev, out, N);
}

// Round 4
// 268.986 us; speedup vs baseline: 1.0522x; 1.0100x over previous
//
#include <hip/hip_runtime.h>
#include <math.h>

#define EPS 1e-8f

typedef float nfloat4 __attribute__((ext_vector_type(4)));

__device__ __forceinline__ float softplus_f(float x) {
    return (x > 20.0f) ? x : log1pf(expf(x));
}
__device__ __forceinline__ float sigmoid_f(float x) {
    return 1.0f / (1.0f + expf(-x));
}

// controls per b (792 floats): keys[4][64] | erase[4][64] | write[4][64]
//   | betas[4] | gates[4] | shifts[4][3] | gammas[4]

// -------------------------------------------------------------------------
// Kernel A: scores[b,h,n] = beta_h * dot(tanh(key_h), mem[b,n])
//                           / (|mem[b,n]| * |tanh(key_h)| + EPS)
// block = 256 threads (rq = t>>4 in 0..15, lane = t&15); 128 rows/block
// (rows rq+16j, j=0..7 -> 8 independent float4 loads in flight per thread).
// grid = (N/128, B). Key prep (tanh, norm, beta) recomputed per block.
// -------------------------------------------------------------------------
__global__ __launch_bounds__(256)
void score_kernel(const float* __restrict__ memory,
                  const float* __restrict__ controls,
                  float* __restrict__ scores, int N)
{
    int b = blockIdx.y;
    int nbase = blockIdx.x * 128;
    int t = threadIdx.x;
    int rq = t >> 4;      // 0..15
    int lane = t & 15;    // 0..15

    __shared__ float kk[256];
    __shared__ float betas_s[4], knorm_s[4];
    __shared__ float sc[4][128];

    const float* c = controls + (size_t)b * 792;

    // per-block key prep: wave h handles head h (h = t>>6, w = t&63)
    {
        int h = t >> 6, w = t & 63;
        float kt = tanhf(c[h * 64 + w]);
        kk[h * 64 + w] = kt;
        float nsq = kt * kt;
        #pragma unroll
        for (int m = 1; m < 64; m <<= 1) nsq += __shfl_xor(nsq, m, 64);
        if (w == 0) knorm_s[h] = sqrtf(nsq);
        if (t < 4)  betas_s[t] = softplus_f(c[768 + t]);
    }
    __syncthreads();

    float4 k4[4];
    #pragma unroll
    for (int h = 0; h < 4; h++) k4[h] = ((const float4*)(kk + h * 64))[lane];
    float beta_l[4], knorm_l[4];
    #pragma unroll
    for (int h = 0; h < 4; h++) { beta_l[h] = betas_s[h]; knorm_l[h] = knorm_s[h]; }

    // prefetch 8 rows (independent loads in flight)
    float4 m4[8];
    #pragma unroll
    for (int j = 0; j < 8; j++) {
        int n = nbase + rq + 16 * j;
        m4[j] = ((const float4*)(memory + ((size_t)b * N + n) * 64))[lane];
    }

    #pragma unroll
    for (int j = 0; j < 8; j++) {
        float nsq = m4[j].x * m4[j].x + m4[j].y * m4[j].y
                  + m4[j].z * m4[j].z + m4[j].w * m4[j].w;
        float d[4];
        #pragma unroll
        for (int h = 0; h < 4; h++) {
            d[h] = m4[j].x * k4[h].x + m4[j].y * k4[h].y
                 + m4[j].z * k4[h].z + m4[j].w * k4[h].w;
        }
        #pragma unroll
        for (int m = 1; m < 16; m <<= 1) {
            nsq += __shfl_xor(nsq, m, 64);
            #pragma unroll
            for (int h = 0; h < 4; h++) d[h] += __shfl_xor(d[h], m, 64);
        }
        if (lane == 0) {
            float mn = sqrtf(nsq);
            int row = rq + 16 * j;
            #pragma unroll
            for (int h = 0; h < 4; h++)
                sc[h][row] = beta_l[h] * d[h] / (mn * knorm_l[h] + EPS);
        }
    }
    __syncthreads();
    // 512 values out: 256 threads x 2, coalesced in 128-float runs
    #pragma unroll
    for (int k = 0; k < 2; k++) {
        int idx = t + k * 256;
        int h = idx >> 7, i = idx & 127;
        scores[((size_t)b * 4 + h) * N + nbase + i] = sc[h][i];
    }
}

// -------------------------------------------------------------------------
// Kernel B: softmax -> interp -> shift -> sharpen -> normalize.
// One 1024-thread block per (b,h); float4 I/O; in-place scores -> w_dist.
// Scalar control transforms recomputed redundantly per thread (6 floats).
// -------------------------------------------------------------------------
__device__ __forceinline__ float block_reduce_sum(float v, float* red) {
    #pragma unroll
    for (int m = 1; m < 64; m <<= 1) v += __shfl_xor(v, m, 64);
    int wid = threadIdx.x >> 6;
    __syncthreads();
    if ((threadIdx.x & 63) == 0) red[wid] = v;
    __syncthreads();
    float r = red[0];
    #pragma unroll
    for (int i = 1; i < 16; i++) r += red[i];
    return r;
}
__device__ __forceinline__ float block_reduce_max(float v, float* red) {
    #pragma unroll
    for (int m = 1; m < 64; m <<= 1) v = fmaxf(v, __shfl_xor(v, m, 64));
    int wid = threadIdx.x >> 6;
    __syncthreads();
    if ((threadIdx.x & 63) == 0) red[wid] = v;
    __syncthreads();
    float r = red[0];
    #pragma unroll
    for (int i = 1; i < 16; i++) r = fmaxf(r, red[i]);
    return r;
}

__global__ __launch_bounds__(1024)
void weights_kernel(float* __restrict__ scores,
                    const float* __restrict__ prev,
                    const float* __restrict__ controls, int N)
{
    int bh = blockIdx.x;
    int b = bh >> 2, h = bh & 3;
    int t = threadIdx.x;
    const float* c = controls + (size_t)b * 792;

    float gate  = sigmoid_f(c[772 + h]);
    float r0 = c[776 + h * 3 + 0];
    float r1 = c[776 + h * 3 + 1];
    float r2 = c[776 + h * 3 + 2];
    float rmx = fmaxf(r0, fmaxf(r1, r2));
    float e0 = expf(r0 - rmx), e1 = expf(r1 - rmx), e2 = expf(r2 - rmx);
    float sinv = 1.0f / (e0 + e1 + e2);
    float s0 = e0 * sinv, s1 = e1 * sinv, s2 = e2 * sinv;
    float gamma = 1.0f + softplus_f(c[788 + h]);

    __shared__ float wi_s[8192];
    __shared__ float red[16];

    float* srow = scores + (size_t)bh * N;
    const float* prow = prev + (size_t)bh * N;
    int half = N >> 1;                    // 4096
    int i0 = 4 * t, i1 = half + 4 * t;

    float4 sa = ((const float4*)srow)[t];
    float4 sb = ((const float4*)srow)[half / 4 + t];
    float4 pa = ((const float4*)prow)[t];
    float4 pb = ((const float4*)prow)[half / 4 + t];

    float mx = fmaxf(fmaxf(fmaxf(sa.x, sa.y), fmaxf(sa.z, sa.w)),
                     fmaxf(fmaxf(sb.x, sb.y), fmaxf(sb.z, sb.w)));
    mx = block_reduce_max(mx, red);

    float ea[4] = { __expf(sa.x - mx), __expf(sa.y - mx), __expf(sa.z - mx), __expf(sa.w - mx) };
    float eb[4] = { __expf(sb.x - mx), __expf(sb.y - mx), __expf(sb.z - mx), __expf(sb.w - mx) };
    float lsum = ea[0] + ea[1] + ea[2] + ea[3] + eb[0] + eb[1] + eb[2] + eb[3];
    float S = block_reduce_sum(lsum, red);
    float invS = 1.0f / S;

    float og = 1.0f - gate;
    float pv_a[4] = { pa.x, pa.y, pa.z, pa.w };
    float pv_b[4] = { pb.x, pb.y, pb.z, pb.w };
    #pragma unroll
    for (int k = 0; k < 4; k++) {
        wi_s[i0 + k] = gate * (ea[k] * invS) + og * pv_a[k];
        wi_s[i1 + k] = gate * (eb[k] * invS) + og * pv_b[k];
    }
    __syncthreads();

    float wsv[8]; float lsum2 = 0.0f;
    #pragma unroll
    for (int cc = 0; cc < 2; cc++) {
        int base = (cc == 0) ? i0 : i1;
        #pragma unroll
        for (int k = 0; k < 4; k++) {
            int i = base + k;
            int im1 = (i == 0) ? (N - 1) : (i - 1);
            int ip1 = (i == N - 1) ? 0 : (i + 1);
            float ws = s0 * wi_s[im1] + s1 * wi_s[i] + s2 * wi_s[ip1];
            // ws strictly > 0 (softmax>0, prev>=0, gate in (0,1)) -> fast pow
            float wp = __expf(gamma * __logf(ws));
            wsv[cc * 4 + k] = wp; lsum2 += wp;
        }
    }
    float T = block_reduce_sum(lsum2, red);
    float invT = 1.0f / (T + EPS);

    float4 oa = make_float4(wsv[0] * invT, wsv[1] * invT, wsv[2] * invT, wsv[3] * invT);
    float4 ob = make_float4(wsv[4] * invT, wsv[5] * invT, wsv[6] * invT, wsv[7] * invT);
    ((float4*)srow)[t] = oa;
    ((float4*)srow)[half / 4 + t] = ob;
}

// -------------------------------------------------------------------------
// Kernel C: out[b,n,w] = mem * prod_h(1 - wd[h,n]*erase[h,w]) + sum_h wd*write
// block = 256 threads; 128 rows/block; 8 rows/thread (8 float4 in flight).
// erase/write vectors recomputed per block from controls (cheap, L2-hot).
// Non-temporal out stores: keep L3 for memory[] (out+mem = 256 MiB = L3).
// grid = B * N/128.
// -------------------------------------------------------------------------
__global__ __launch_bounds__(256)
void output_kernel(const float* __restrict__ memory,
                   const float* __restrict__ wdist,
                   const float* __restrict__ controls,
                   float* __restrict__ out, int N)
{
    int t = threadIdx.x;
    int blocksPerB = N >> 7;
    int b = blockIdx.x / blocksPerB;
    int nbase = (blockIdx.x % blocksPerB) << 7;

    __shared__ float es[256], wv[256], wd_s[512];
    const float* c = controls + (size_t)b * 792;
    es[t] = sigmoid_f(c[256 + t]);
    wv[t] = tanhf(c[512 + t]);
    #pragma unroll
    for (int k = 0; k < 2; k++) {
        int idx = t + k * 256;
        int h = idx >> 7, i = idx & 127;
        wd_s[idx] = wdist[((size_t)b * 4 + h) * N + nbase + i];
    }
    __syncthreads();

    int rq = t >> 4, lane = t & 15;

    float4 e4[4], w4[4];
    #pragma unroll
    for (int h = 0; h < 4; h++) {
        e4[h] = ((const float4*)(es + h * 64))[lane];
        w4[h] = ((const float4*)(wv + h * 64))[lane];
    }

    float4 m4[8];
    #pragma unroll
    for (int j = 0; j < 8; j++) {
        int n = nbase + rq + 16 * j;
        m4[j] = ((const float4*)(memory + ((size_t)b * N + n) * 64))[lane];
    }

    #pragma unroll
    for (int j = 0; j < 8; j++) {
        int row = rq + 16 * j;
        int n = nbase + row;
        float4 pe = make_float4(1.f, 1.f, 1.f, 1.f);
        float4 up = make_float4(0.f, 0.f, 0.f, 0.f);
        #pragma unroll
        for (int h = 0; h < 4; h++) {
            float f = wd_s[h * 128 + row];
            pe.x *= 1.0f - f * e4[h].x;  pe.y *= 1.0f - f * e4[h].y;
            pe.z *= 1.0f - f * e4[h].z;  pe.w *= 1.0f - f * e4[h].w;
            up.x += f * w4[h].x;  up.y += f * w4[h].y;
            up.z += f * w4[h].z;  up.w += f * w4[h].w;
        }
        nfloat4 o;
        o.x = m4[j].x * pe.x + up.x;
        o.y = m4[j].y * pe.y + up.y;
        o.z = m4[j].z * pe.z + up.z;
        o.w = m4[j].w * pe.w + up.w;
        nfloat4* op = ((nfloat4*)(out + ((size_t)b * N + n) * 64)) + lane;
        __builtin_nontemporal_store(o, op);
    }
}

// -------------------------------------------------------------------------
extern "C" void kernel_launch(void* const* d_in, const int* in_sizes, int n_in,
                              void* d_out, int out_size, void* d_ws, size_t ws_size,
                              hipStream_t stream) {
    const float* memory   = (const float*)d_in[0];
    const float* controls = (const float*)d_in[1];
    const float* prev     = (const float*)d_in[2];
    float* out = (float*)d_out;

    int B = in_sizes[1] / 792;            // H*(3W+6) = 792
    int N = in_sizes[0] / (B * 64);       // W = 64

    float* scores = (float*)d_ws;         // B*4*N floats (in-place -> w_dist)

    score_kernel<<<dim3(N / 128, B), 256, 0, stream>>>(memory, controls, scores, N);
    weights_kernel<<<B * 4, 1024, 0, stream>>>(scores, prev, controls, N);
    output_kernel<<<B * (N / 128), 256, 0, stream>>>(memory, scores, controls, out, N);
}